// Round 10
// baseline (608.171 us; speedup 1.0000x reference)
//
#include <hip/hip_runtime.h>

#define N_NODES 500000
#define N_EDGES 8000000
#define N_GRAPHS 4096
#define IN_DIM 9
#define HID 64
#define TILE 256             // nodes per wave-private bucket
#define TSR 12               // LDS tile row stride -> 48 B (f4,f4,scalar)
#define NKEYS 2048           // padded key space (used: 1954)
#define NKEYS_USED ((N_NODES + TILE - 1) / TILE)   // 1954
#define NSCAT 256            // hist/scatter chunks
#define CHUNK (N_EDGES / NSCAT)                    // 31250
#define HSB 1024             // hist/scatter block threads
#define RB 256               // reduce block threads (4 waves)
#define WPB 4
#define RGRID ((NKEYS_USED + WPB - 1) / WPB)       // 489
#define SCAN_N (NKEYS * NSCAT)                     // 524288
#define SCAN_BLOCKS (SCAN_N / 1024)                // 512
#define NW 8                 // src windows: src>>16
#define CAP 5120             // winsort LDS capacity (mean 4096, sd 64 -> safe)
#define NSETS 8              // XCD sets (blockIdx % 8 heuristic)

// ---------------- xpad: x[N][9] -> xa[N][8] (32B rows) + xb[N] --------------
__global__ void gin_xpad(const float* __restrict__ x,
                         float* __restrict__ xa, float* __restrict__ xb) {
    int i = blockIdx.x * blockDim.x + threadIdx.x;
    const int TOT = N_NODES * IN_DIM;
    if (i < TOT) {
        int n = i / IN_DIM, k = i - n * IN_DIM;
        float val = x[i];
        if (k < 8) xa[n * 8 + k] = val;
        else       xb[n] = val;
    }
}

// ---------------- precompute: v = w2@w3, c = b2.w3, out[g] = b3 -------------
__global__ void gin_precompute(const float* __restrict__ w2,
                               const float* __restrict__ b2,
                               const float* __restrict__ w3,
                               const float* __restrict__ b3,
                               float* __restrict__ out,
                               float* __restrict__ v,
                               float* __restrict__ c) {
    int g = blockIdx.x * blockDim.x + threadIdx.x;
    if (g < N_GRAPHS) out[g] = b3[0];
    if (blockIdx.x == 0) {
        int k = threadIdx.x;
        if (k < HID) {
            float acc = 0.f;
            #pragma unroll
            for (int j = 0; j < HID; ++j) acc += w2[k * HID + j] * w3[j];
            v[k] = acc;
        } else if (k == HID) {
            float acc = 0.f;
            #pragma unroll
            for (int j = 0; j < HID; ++j) acc += b2[j] * w3[j];
            *c = acc;
        }
    }
}

// ---------------- hist: cnt[key*NSCAT + col], col = (s&7)*32 + (s>>3) -------
// Column regrouping puts the 32 chunks of one XCD-set adjacent, so after the
// flat scan each (key,set) region is contiguous.
__global__ __launch_bounds__(HSB) void gin_hist(const int* __restrict__ ei,
                                                int* __restrict__ cnt) {
    __shared__ int h[NKEYS];
    const int t = threadIdx.x, s = blockIdx.x;
    const int col = (s & 7) * 32 + (s >> 3);
    for (int b = t; b < NKEYS; b += HSB) h[b] = 0;
    __syncthreads();
    const int* dst = ei + N_EDGES;
    const int e0 = s * CHUNK, e1 = e0 + CHUNK;
    for (int e = e0 + t; e < e1; e += HSB)
        atomicAdd(&h[dst[e] >> 8], 1);
    __syncthreads();
    for (int b = t; b < NKEYS; b += HSB)
        cnt[b * NSCAT + col] = h[b];
}

// ---------------- parallel exclusive scan of cnt[SCAN_N] --------------------
__global__ __launch_bounds__(256) void gin_scan_a(int* __restrict__ cnt,
                                                  int* __restrict__ aux) {
    __shared__ int wtot[4];
    const int t = threadIdx.x, blk = blockIdx.x;
    int4* p = (int4*)(cnt + blk * 1024);
    int4 vv = p[t];
    int s0 = vv.x, s1 = s0 + vv.y, s2 = s1 + vv.z, s3 = s2 + vv.w;
    int lane = t & 63, w = t >> 6;
    int ws = s3;
    #pragma unroll
    for (int off = 1; off < 64; off <<= 1) {
        int o = __shfl_up(ws, off);
        if (lane >= off) ws += o;
    }
    if (lane == 63) wtot[w] = ws;
    __syncthreads();
    int wbase = 0;
    for (int i = 0; i < w; ++i) wbase += wtot[i];
    int excl = wbase + (ws - s3);
    int4 o4;
    o4.x = excl; o4.y = excl + s0; o4.z = excl + s1; o4.w = excl + s2;
    p[t] = o4;
    if (t == 255) aux[blk] = wbase + ws;
}

__global__ __launch_bounds__(64) void gin_scan_b(int* __restrict__ aux) {
    const int t = threadIdx.x;
    int4* p = (int4*)aux;
    int4 a = p[2 * t], bq = p[2 * t + 1];
    int s0 = a.x, s1 = s0 + a.y, s2 = s1 + a.z, s3 = s2 + a.w;
    int s4 = s3 + bq.x, s5 = s4 + bq.y, s6 = s5 + bq.z, s7 = s6 + bq.w;
    int ws = s7;
    #pragma unroll
    for (int off = 1; off < 64; off <<= 1) {
        int o = __shfl_up(ws, off);
        if (t >= off) ws += o;
    }
    int excl = ws - s7;
    int4 o0, o1;
    o0.x = excl; o0.y = excl + s0; o0.z = excl + s1; o0.w = excl + s2;
    o1.x = excl + s3; o1.y = excl + s4; o1.z = excl + s5; o1.w = excl + s6;
    p[2 * t] = o0; p[2 * t + 1] = o1;
}

__global__ __launch_bounds__(256) void gin_scan_c(int* __restrict__ cnt,
                                                  const int* __restrict__ aux) {
    const int t = threadIdx.x, blk = blockIdx.x;
    int base = aux[blk];
    int4* p = (int4*)(cnt + blk * 1024);
    int4 vv = p[t];
    vv.x += base; vv.y += base; vv.z += base; vv.w += base;
    p[t] = vv;
}

// ---------------- curinit: gcur[key*8 + set] = base of (key,set) region -----
__global__ __launch_bounds__(256) void gin_curinit(const int* __restrict__ cnt,
                                                   int* __restrict__ gcur) {
    int i = blockIdx.x * blockDim.x + threadIdx.x;
    if (i < NKEYS * NSETS)
        gcur[i] = cnt[(i >> 3) * NSCAT + (i & 7) * 32];
}

// ---------------- scatter: global per-(key,set) cursors, XCD-local append ---
// All blocks with the same blockIdx%8 (one XCD under the round-robin
// heuristic) append into the same (key,set) regions, so partial lines are
// assembled in a single L2. Order within a bucket is irrelevant.
__global__ __launch_bounds__(HSB) void gin_scatter(const int* __restrict__ ei,
                                                   int* __restrict__ gcur,
                                                   unsigned int* __restrict__ packed) {
    const int t = threadIdx.x, s = blockIdx.x;
    const int sigma = s & 7;
    const int* src = ei;
    const int* dst = ei + N_EDGES;
    const int e0 = s * CHUNK, e1 = e0 + CHUNK;
    for (int e = e0 + t; e < e1; e += HSB) {
        int d = dst[e];
        int key = d >> 8;
        int local = d & (TILE - 1);
        int pos = atomicAdd(&gcur[key * 8 + sigma], 1);
        packed[pos] = (unsigned int)src[e] | ((unsigned int)local << 19);
    }
}

// ---------------- winsort: reorder each bucket's edges by src window --------
__global__ __launch_bounds__(256) void gin_winsort(unsigned int* __restrict__ packed,
                                                   const int* __restrict__ cnt) {
    __shared__ unsigned int E[CAP];
    __shared__ unsigned int F[CAP];
    __shared__ int cw[NW * 256];
    __shared__ int winBase[NW];
    __shared__ int wt[NW];
    const int t = threadIdx.x, bucket = blockIdx.x;
    const int beg = cnt[bucket * NSCAT];
    const int end = cnt[(bucket + 1) * NSCAT];
    const int n = end - beg;
    if (n > CAP) return;                      // identity fallback (rare/never)

    for (int i = t; i < n; i += 256) E[i] = packed[beg + i];
    __syncthreads();

    int c[NW];
    #pragma unroll
    for (int w = 0; w < NW; ++w) c[w] = 0;
    for (int i = t; i < n; i += 256) { int w = (E[i] & 0x7FFFFu) >> 16; c[w]++; }
    #pragma unroll
    for (int w = 0; w < NW; ++w) cw[w * 256 + t] = c[w];
    __syncthreads();

    const int lane = t & 63, wv = t >> 6;
    for (int rep = 0; rep < 2; ++rep) {
        int w = wv + rep * 4;
        int carry = 0;
        #pragma unroll
        for (int chunkk = 0; chunkk < 4; ++chunkk) {
            int idx = chunkk * 64 + lane;
            int val = cw[w * 256 + idx];
            int sc = val;
            #pragma unroll
            for (int off = 1; off < 64; off <<= 1) {
                int o = __shfl_up(sc, off);
                if (lane >= off) sc += o;
            }
            cw[w * 256 + idx] = sc - val + carry;
            carry += __shfl(sc, 63);
        }
        if (lane == 0) wt[w] = carry;
    }
    __syncthreads();
    if (t == 0) {
        int run = 0;
        #pragma unroll
        for (int w = 0; w < NW; ++w) { winBase[w] = run; run += wt[w]; }
    }
    __syncthreads();

    int runc[NW];
    #pragma unroll
    for (int w = 0; w < NW; ++w) runc[w] = 0;
    for (int i = t; i < n; i += 256) {
        unsigned int pk = E[i];
        int w = (pk & 0x7FFFFu) >> 16;
        int pos = winBase[w] + cw[w * 256 + t] + runc[w]++;
        F[pos] = pk;
    }
    __syncthreads();
    for (int i = t; i < n; i += 256) packed[beg + i] = F[i];
}

// ---------------- reduce: wave-private tile, NO aggregation atomics ---------
__global__ __launch_bounds__(RB) void gin_reduce(
    const unsigned int* __restrict__ packed,
    const int* __restrict__ cnt,
    const float* __restrict__ xa,
    const float* __restrict__ xb,
    const int* __restrict__ batch,
    const float* __restrict__ w1,
    const float* __restrict__ b1,
    const float* __restrict__ v,
    const float* __restrict__ c,
    float* __restrict__ out)
{
    __shared__ float tile[WPB * TILE * TSR];   // 48 KB, one 12 KB slice per wave
    __shared__ float w1s[IN_DIM * HID];
    __shared__ float b1s[HID];
    __shared__ float vs[HID];
    __shared__ float cs;

    const int t = threadIdx.x;
    const int wave = t >> 6, lane = t & 63;

    for (int i = t; i < WPB * TILE * TSR; i += RB) tile[i] = 0.f;
    for (int i = t; i < IN_DIM * HID; i += RB) w1s[i] = w1[i];
    if (t < HID) { b1s[t] = b1[t]; vs[t] = v[t]; }
    if (t == 0) cs = *c;
    __syncthreads();

    const int bucket = blockIdx.x * WPB + wave;
    float* tw = tile + wave * TILE * TSR;
    const int beg = cnt[bucket * NSCAT];
    const int end = cnt[(bucket + 1) * NSCAT];   // padded keys hold N_EDGES

    for (int p0 = beg; p0 < end; p0 += 64) {
        int p = p0 + lane;
        bool valid = p < end;
        unsigned int pk = valid ? packed[p] : 0u;
        int local = (int)(pk >> 19);             // 0..255
        int src = (int)(pk & 0x7FFFFu);
        const float4* xr = (const float4*)(xa + (size_t)src * 8);
        float4 a0 = xr[0], a1 = xr[1];
        float a2 = xb[src];

        unsigned long long active = __ballot(valid);
        while (active) {
            unsigned long long m = active;
            #pragma unroll
            for (int bq = 0; bq < 8; ++bq) {
                unsigned long long bal = __ballot((local >> bq) & 1);
                m &= ((local >> bq) & 1) ? bal : ~bal;
            }
            unsigned long long mybit = 1ULL << lane;
            bool lead = ((active & mybit) != 0ULL) && ((m & (mybit - 1ULL)) == 0ULL);
            unsigned long long lmask = __ballot(lead);
            if (lead) {
                float4* row = (float4*)(tw + local * TSR);
                float4 r0 = row[0], r1 = row[1];
                float r2 = tw[local * TSR + 8];
                r0.x += a0.x; r0.y += a0.y; r0.z += a0.z; r0.w += a0.w;
                r1.x += a1.x; r1.y += a1.y; r1.z += a1.z; r1.w += a1.w;
                row[0] = r0; row[1] = r1;
                tw[local * TSR + 8] = r2 + a2;
            }
            active &= ~lmask;
        }
    }
    // no barrier needed: tile slice is wave-private from here on

    // fused MLP + scalar collapse + segmented pooled reduction
    #pragma unroll
    for (int g = 0; g < TILE / 64; ++g) {
        int n = g * 64 + lane;
        int node = bucket * TILE + n;
        float s = 0.f;
        int b = -1;
        if (node < N_NODES) {
            const float4* xr = (const float4*)(xa + (size_t)node * 8);
            float4 q0 = xr[0], q1 = xr[1];
            float tv[IN_DIM];
            tv[0] = q0.x + tw[n * TSR + 0];
            tv[1] = q0.y + tw[n * TSR + 1];
            tv[2] = q0.z + tw[n * TSR + 2];
            tv[3] = q0.w + tw[n * TSR + 3];
            tv[4] = q1.x + tw[n * TSR + 4];
            tv[5] = q1.y + tw[n * TSR + 5];
            tv[6] = q1.z + tw[n * TSR + 6];
            tv[7] = q1.w + tw[n * TSR + 7];
            tv[8] = xb[node] + tw[n * TSR + 8];
            s = cs;
            #pragma unroll
            for (int j = 0; j < HID; ++j) {
                float z = b1s[j];
                #pragma unroll
                for (int k = 0; k < IN_DIM; ++k)
                    z = fmaf(tv[k], w1s[k * HID + j], z);
                s += fmaxf(z, 0.f) * vs[j];
            }
            b = batch[node];
        }
        #pragma unroll
        for (int off = 1; off < 64; off <<= 1) {
            float so = __shfl_up(s, off);
            int bo = __shfl_up(b, off);
            if (lane >= off && bo == b) s += so;
        }
        int nb = __shfl_down(b, 1);
        bool tail = (lane == 63) || (nb != b);
        if (tail && b >= 0) atomicAdd(&out[b], s);
    }
}

extern "C" void kernel_launch(void* const* d_in, const int* in_sizes, int n_in,
                              void* d_out, int out_size, void* d_ws, size_t ws_size,
                              hipStream_t stream) {
    const float* x     = (const float*)d_in[0];
    const int*   ei    = (const int*)d_in[1];
    const int*   batch = (const int*)d_in[2];
    const float* w1    = (const float*)d_in[3];
    const float* b1    = (const float*)d_in[4];
    const float* w2    = (const float*)d_in[5];
    const float* b2    = (const float*)d_in[6];
    const float* w3    = (const float*)d_in[7];
    const float* b3    = (const float*)d_in[8];
    float* out = (float*)d_out;

    // workspace (~52.2 MB)
    float* xa = (float*)d_ws;                                           // 16 MB
    float* xb = xa + (size_t)N_NODES * 8;                               // 2 MB
    unsigned int* packed = (unsigned int*)(xb + N_NODES);               // 32 MB
    int* cnt = (int*)(packed + N_EDGES);                                // 2 MB
    int* aux = cnt + SCAN_N;                                            // 512 ints
    int* gcur = aux + SCAN_BLOCKS;                                      // 16K ints
    float* v = (float*)(gcur + NKEYS * NSETS);                          // 64 floats
    float* c = v + HID;                                                 // 1 float

    gin_xpad<<<(N_NODES * IN_DIM + 255) / 256, 256, 0, stream>>>(x, xa, xb);
    gin_precompute<<<(N_GRAPHS + 255) / 256, 256, 0, stream>>>(w2, b2, w3, b3, out, v, c);
    gin_hist<<<NSCAT, HSB, 0, stream>>>(ei, cnt);
    gin_scan_a<<<SCAN_BLOCKS, 256, 0, stream>>>(cnt, aux);
    gin_scan_b<<<1, 64, 0, stream>>>(aux);
    gin_scan_c<<<SCAN_BLOCKS, 256, 0, stream>>>(cnt, aux);
    gin_curinit<<<(NKEYS * NSETS + 255) / 256, 256, 0, stream>>>(cnt, gcur);
    gin_scatter<<<NSCAT, HSB, 0, stream>>>(ei, gcur, packed);
    gin_winsort<<<NKEYS_USED, 256, 0, stream>>>(packed, cnt);
    gin_reduce<<<RGRID, RB, 0, stream>>>(packed, cnt, xa, xb, batch, w1, b1, v, c, out);
}

// Round 11
// 483.042 us; speedup vs baseline: 1.2590x; 1.2590x over previous
//
#include <hip/hip_runtime.h>

#define N_NODES 500000
#define N_EDGES 8000000
#define N_GRAPHS 4096
#define IN_DIM 9
#define HID 64
#define TILE 256             // nodes per wave-private bucket
#define TSR 12               // LDS tile row stride -> 48 B (f4,f4,scalar)
#define NKEYS 2048           // padded key space (used: 1954)
#define NKEYS_USED ((N_NODES + TILE - 1) / TILE)   // 1954
#define NSCAT 256            // hist chunks (scan layout)
#define CHUNK (N_EDGES / NSCAT)                    // 31250
#define NSC2 128             // scatter blocks (each covers 2 hist chunks)
#define SCHUNK (N_EDGES / NSC2)                    // 62500
#define HSB 1024             // hist/scatter block threads
#define RB 256               // reduce block threads (4 waves)
#define WPB 4
#define RGRID ((NKEYS_USED + WPB - 1) / WPB)       // 489
#define SCAN_N (NKEYS * NSCAT)                     // 524288
#define SCAN_BLOCKS (SCAN_N / 1024)                // 512
#define NW 8                 // src windows: src>>16
#define CAP 5120             // winsort LDS capacity (mean 4096, sd 64 -> safe)

// ---------------- xpad: x[N][9] -> xa[N][8] (32B rows) + xb[N] --------------
__global__ void gin_xpad(const float* __restrict__ x,
                         float* __restrict__ xa, float* __restrict__ xb) {
    int i = blockIdx.x * blockDim.x + threadIdx.x;
    const int TOT = N_NODES * IN_DIM;
    if (i < TOT) {
        int n = i / IN_DIM, k = i - n * IN_DIM;
        float val = x[i];
        if (k < 8) xa[n * 8 + k] = val;
        else       xb[n] = val;
    }
}

// ---------------- precompute: v = w2@w3, c = b2.w3, out[g] = b3 -------------
__global__ void gin_precompute(const float* __restrict__ w2,
                               const float* __restrict__ b2,
                               const float* __restrict__ w3,
                               const float* __restrict__ b3,
                               float* __restrict__ out,
                               float* __restrict__ v,
                               float* __restrict__ c) {
    int g = blockIdx.x * blockDim.x + threadIdx.x;
    if (g < N_GRAPHS) out[g] = b3[0];
    if (blockIdx.x == 0) {
        int k = threadIdx.x;
        if (k < HID) {
            float acc = 0.f;
            #pragma unroll
            for (int j = 0; j < HID; ++j) acc += w2[k * HID + j] * w3[j];
            v[k] = acc;
        } else if (k == HID) {
            float acc = 0.f;
            #pragma unroll
            for (int j = 0; j < HID; ++j) acc += b2[j] * w3[j];
            *c = acc;
        }
    }
}

// ---------------- hist: cnt[key*NSCAT + s], key = dst>>8 --------------------
__global__ __launch_bounds__(HSB) void gin_hist(const int* __restrict__ ei,
                                                int* __restrict__ cnt) {
    __shared__ int h[NKEYS];
    const int t = threadIdx.x, s = blockIdx.x;
    for (int b = t; b < NKEYS; b += HSB) h[b] = 0;
    __syncthreads();
    const int* dst = ei + N_EDGES;
    const int e0 = s * CHUNK, e1 = e0 + CHUNK;
    for (int e = e0 + t; e < e1; e += HSB)
        atomicAdd(&h[dst[e] >> 8], 1);
    __syncthreads();
    for (int b = t; b < NKEYS; b += HSB)
        cnt[b * NSCAT + s] = h[b];
}

// ---------------- parallel exclusive scan of cnt[SCAN_N] --------------------
__global__ __launch_bounds__(256) void gin_scan_a(int* __restrict__ cnt,
                                                  int* __restrict__ aux) {
    __shared__ int wtot[4];
    const int t = threadIdx.x, blk = blockIdx.x;
    int4* p = (int4*)(cnt + blk * 1024);
    int4 vv = p[t];
    int s0 = vv.x, s1 = s0 + vv.y, s2 = s1 + vv.z, s3 = s2 + vv.w;
    int lane = t & 63, w = t >> 6;
    int ws = s3;
    #pragma unroll
    for (int off = 1; off < 64; off <<= 1) {
        int o = __shfl_up(ws, off);
        if (lane >= off) ws += o;
    }
    if (lane == 63) wtot[w] = ws;
    __syncthreads();
    int wbase = 0;
    for (int i = 0; i < w; ++i) wbase += wtot[i];
    int excl = wbase + (ws - s3);
    int4 o4;
    o4.x = excl; o4.y = excl + s0; o4.z = excl + s1; o4.w = excl + s2;
    p[t] = o4;
    if (t == 255) aux[blk] = wbase + ws;
}

__global__ __launch_bounds__(64) void gin_scan_b(int* __restrict__ aux) {
    const int t = threadIdx.x;
    int4* p = (int4*)aux;
    int4 a = p[2 * t], bq = p[2 * t + 1];
    int s0 = a.x, s1 = s0 + a.y, s2 = s1 + a.z, s3 = s2 + a.w;
    int s4 = s3 + bq.x, s5 = s4 + bq.y, s6 = s5 + bq.z, s7 = s6 + bq.w;
    int ws = s7;
    #pragma unroll
    for (int off = 1; off < 64; off <<= 1) {
        int o = __shfl_up(ws, off);
        if (t >= off) ws += o;
    }
    int excl = ws - s7;
    int4 o0, o1;
    o0.x = excl; o0.y = excl + s0; o0.z = excl + s1; o0.w = excl + s2;
    o1.x = excl + s3; o1.y = excl + s4; o1.z = excl + s5; o1.w = excl + s6;
    p[2 * t] = o0; p[2 * t + 1] = o1;
}

__global__ __launch_bounds__(256) void gin_scan_c(int* __restrict__ cnt,
                                                  const int* __restrict__ aux) {
    const int t = threadIdx.x, blk = blockIdx.x;
    int base = aux[blk];
    int4* p = (int4*)(cnt + blk * 1024);
    int4 vv = p[t];
    vv.x += base; vv.y += base; vv.z += base; vv.w += base;
    p[t] = vv;
}

// ---------------- scatter: packed[pos] = src | (local<<19), key = dst>>8 ----
// 128 blocks; block s owns hist columns {2s, 2s+1}, which are adjacent in the
// scan layout, so each (key, block) region is contiguous and ~30 edges long
// (vs 16 at 256 blocks) -> fewer partial-line boundaries, lower write amp.
__global__ __launch_bounds__(HSB) void gin_scatter(const int* __restrict__ ei,
                                                   const int* __restrict__ cnt,
                                                   unsigned int* __restrict__ packed) {
    __shared__ int cur[NKEYS];
    const int t = threadIdx.x, s = blockIdx.x;
    for (int b = t; b < NKEYS; b += HSB) cur[b] = cnt[b * NSCAT + 2 * s];
    __syncthreads();
    const int* src = ei;
    const int* dst = ei + N_EDGES;
    const int e0 = s * SCHUNK, e1 = e0 + SCHUNK;
    for (int e = e0 + t; e < e1; e += HSB) {
        int d = dst[e];
        int key = d >> 8;
        int local = d & (TILE - 1);
        int pos = atomicAdd(&cur[key], 1);
        packed[pos] = (unsigned int)src[e] | ((unsigned int)local << 19);
    }
}

// ---------------- winsort: reorder each bucket's edges by src window --------
__global__ __launch_bounds__(256) void gin_winsort(unsigned int* __restrict__ packed,
                                                   const int* __restrict__ cnt) {
    __shared__ unsigned int E[CAP];
    __shared__ unsigned int F[CAP];
    __shared__ int cw[NW * 256];
    __shared__ int winBase[NW];
    __shared__ int wt[NW];
    const int t = threadIdx.x, bucket = blockIdx.x;
    const int beg = cnt[bucket * NSCAT];
    const int end = cnt[(bucket + 1) * NSCAT];
    const int n = end - beg;
    if (n > CAP) return;                      // identity fallback (rare/never)

    for (int i = t; i < n; i += 256) E[i] = packed[beg + i];
    __syncthreads();

    int c[NW];
    #pragma unroll
    for (int w = 0; w < NW; ++w) c[w] = 0;
    for (int i = t; i < n; i += 256) { int w = (E[i] & 0x7FFFFu) >> 16; c[w]++; }
    #pragma unroll
    for (int w = 0; w < NW; ++w) cw[w * 256 + t] = c[w];
    __syncthreads();

    const int lane = t & 63, wv = t >> 6;
    for (int rep = 0; rep < 2; ++rep) {
        int w = wv + rep * 4;
        int carry = 0;
        #pragma unroll
        for (int chunkk = 0; chunkk < 4; ++chunkk) {
            int idx = chunkk * 64 + lane;
            int val = cw[w * 256 + idx];
            int sc = val;
            #pragma unroll
            for (int off = 1; off < 64; off <<= 1) {
                int o = __shfl_up(sc, off);
                if (lane >= off) sc += o;
            }
            cw[w * 256 + idx] = sc - val + carry;
            carry += __shfl(sc, 63);
        }
        if (lane == 0) wt[w] = carry;
    }
    __syncthreads();
    if (t == 0) {
        int run = 0;
        #pragma unroll
        for (int w = 0; w < NW; ++w) { winBase[w] = run; run += wt[w]; }
    }
    __syncthreads();

    int runc[NW];
    #pragma unroll
    for (int w = 0; w < NW; ++w) runc[w] = 0;
    for (int i = t; i < n; i += 256) {
        unsigned int pk = E[i];
        int w = (pk & 0x7FFFFu) >> 16;
        int pos = winBase[w] + cw[w * 256 + t] + runc[w]++;
        F[pos] = pk;
    }
    __syncthreads();
    for (int i = t; i < n; i += 256) packed[beg + i] = F[i];
}

// ---------------- reduce: wave-private tile, NO aggregation atomics ---------
__global__ __launch_bounds__(RB) void gin_reduce(
    const unsigned int* __restrict__ packed,
    const int* __restrict__ cnt,
    const float* __restrict__ xa,
    const float* __restrict__ xb,
    const int* __restrict__ batch,
    const float* __restrict__ w1,
    const float* __restrict__ b1,
    const float* __restrict__ v,
    const float* __restrict__ c,
    float* __restrict__ out)
{
    __shared__ float tile[WPB * TILE * TSR];   // 48 KB, one 12 KB slice per wave
    __shared__ float w1s[IN_DIM * HID];
    __shared__ float b1s[HID];
    __shared__ float vs[HID];
    __shared__ float cs;

    const int t = threadIdx.x;
    const int wave = t >> 6, lane = t & 63;

    for (int i = t; i < WPB * TILE * TSR; i += RB) tile[i] = 0.f;
    for (int i = t; i < IN_DIM * HID; i += RB) w1s[i] = w1[i];
    if (t < HID) { b1s[t] = b1[t]; vs[t] = v[t]; }
    if (t == 0) cs = *c;
    __syncthreads();

    const int bucket = blockIdx.x * WPB + wave;
    float* tw = tile + wave * TILE * TSR;
    const int beg = cnt[bucket * NSCAT];
    const int end = cnt[(bucket + 1) * NSCAT];   // padded keys hold N_EDGES

    for (int p0 = beg; p0 < end; p0 += 64) {
        int p = p0 + lane;
        bool valid = p < end;
        unsigned int pk = valid ? packed[p] : 0u;
        int local = (int)(pk >> 19);             // 0..255
        int src = (int)(pk & 0x7FFFFu);
        const float4* xr = (const float4*)(xa + (size_t)src * 8);
        float4 a0 = xr[0], a1 = xr[1];
        float a2 = xb[src];

        unsigned long long active = __ballot(valid);
        while (active) {
            unsigned long long m = active;
            #pragma unroll
            for (int bq = 0; bq < 8; ++bq) {
                unsigned long long bal = __ballot((local >> bq) & 1);
                m &= ((local >> bq) & 1) ? bal : ~bal;
            }
            unsigned long long mybit = 1ULL << lane;
            bool lead = ((active & mybit) != 0ULL) && ((m & (mybit - 1ULL)) == 0ULL);
            unsigned long long lmask = __ballot(lead);
            if (lead) {
                float4* row = (float4*)(tw + local * TSR);
                float4 r0 = row[0], r1 = row[1];
                float r2 = tw[local * TSR + 8];
                r0.x += a0.x; r0.y += a0.y; r0.z += a0.z; r0.w += a0.w;
                r1.x += a1.x; r1.y += a1.y; r1.z += a1.z; r1.w += a1.w;
                row[0] = r0; row[1] = r1;
                tw[local * TSR + 8] = r2 + a2;
            }
            active &= ~lmask;
        }
    }
    // no barrier needed: tile slice is wave-private from here on

    // fused MLP + scalar collapse + segmented pooled reduction
    #pragma unroll
    for (int g = 0; g < TILE / 64; ++g) {
        int n = g * 64 + lane;
        int node = bucket * TILE + n;
        float s = 0.f;
        int b = -1;
        if (node < N_NODES) {
            const float4* xr = (const float4*)(xa + (size_t)node * 8);
            float4 q0 = xr[0], q1 = xr[1];
            float tv[IN_DIM];
            tv[0] = q0.x + tw[n * TSR + 0];
            tv[1] = q0.y + tw[n * TSR + 1];
            tv[2] = q0.z + tw[n * TSR + 2];
            tv[3] = q0.w + tw[n * TSR + 3];
            tv[4] = q1.x + tw[n * TSR + 4];
            tv[5] = q1.y + tw[n * TSR + 5];
            tv[6] = q1.z + tw[n * TSR + 6];
            tv[7] = q1.w + tw[n * TSR + 7];
            tv[8] = xb[node] + tw[n * TSR + 8];
            s = cs;
            #pragma unroll
            for (int j = 0; j < HID; ++j) {
                float z = b1s[j];
                #pragma unroll
                for (int k = 0; k < IN_DIM; ++k)
                    z = fmaf(tv[k], w1s[k * HID + j], z);
                s += fmaxf(z, 0.f) * vs[j];
            }
            b = batch[node];
        }
        #pragma unroll
        for (int off = 1; off < 64; off <<= 1) {
            float so = __shfl_up(s, off);
            int bo = __shfl_up(b, off);
            if (lane >= off && bo == b) s += so;
        }
        int nb = __shfl_down(b, 1);
        bool tail = (lane == 63) || (nb != b);
        if (tail && b >= 0) atomicAdd(&out[b], s);
    }
}

extern "C" void kernel_launch(void* const* d_in, const int* in_sizes, int n_in,
                              void* d_out, int out_size, void* d_ws, size_t ws_size,
                              hipStream_t stream) {
    const float* x     = (const float*)d_in[0];
    const int*   ei    = (const int*)d_in[1];
    const int*   batch = (const int*)d_in[2];
    const float* w1    = (const float*)d_in[3];
    const float* b1    = (const float*)d_in[4];
    const float* w2    = (const float*)d_in[5];
    const float* b2    = (const float*)d_in[6];
    const float* w3    = (const float*)d_in[7];
    const float* b3    = (const float*)d_in[8];
    float* out = (float*)d_out;

    // workspace (~52.1 MB)
    float* xa = (float*)d_ws;                                           // 16 MB
    float* xb = xa + (size_t)N_NODES * 8;                               // 2 MB
    unsigned int* packed = (unsigned int*)(xb + N_NODES);               // 32 MB
    int* cnt = (int*)(packed + N_EDGES);                                // 2 MB
    int* aux = cnt + SCAN_N;                                            // 512 ints
    float* v = (float*)(aux + SCAN_BLOCKS);                             // 64 floats
    float* c = v + HID;                                                 // 1 float

    gin_xpad<<<(N_NODES * IN_DIM + 255) / 256, 256, 0, stream>>>(x, xa, xb);
    gin_precompute<<<(N_GRAPHS + 255) / 256, 256, 0, stream>>>(w2, b2, w3, b3, out, v, c);
    gin_hist<<<NSCAT, HSB, 0, stream>>>(ei, cnt);
    gin_scan_a<<<SCAN_BLOCKS, 256, 0, stream>>>(cnt, aux);
    gin_scan_b<<<1, 64, 0, stream>>>(aux);
    gin_scan_c<<<SCAN_BLOCKS, 256, 0, stream>>>(cnt, aux);
    gin_scatter<<<NSC2, HSB, 0, stream>>>(ei, cnt, packed);
    gin_winsort<<<NKEYS_USED, 256, 0, stream>>>(packed, cnt);
    gin_reduce<<<RGRID, RB, 0, stream>>>(packed, cnt, xa, xb, batch, w1, b1, v, c, out);
}

// Round 12
// 393.214 us; speedup vs baseline: 1.5467x; 1.2284x over previous
//
#include <hip/hip_runtime.h>

#define N_NODES 500000
#define N_EDGES 8000000
#define N_GRAPHS 4096
#define IN_DIM 9
#define HID 64
#define TILE 256             // nodes per wave-private bucket
#define TSR 12               // LDS tile row stride -> 48 B (f4,f4,scalar)
#define NKEYS 2048           // padded key space (used: 1954)
#define NKEYS_USED ((N_NODES + TILE - 1) / TILE)   // 1954
#define NSCAT 256            // hist/scatter chunks
#define CHUNK (N_EDGES / NSCAT)                    // 31250
#define HSB 1024             // hist/scatter block threads
#define RB 256               // reduce block threads (4 waves)
#define WPB 4
#define RGRID ((NKEYS_USED + WPB - 1) / WPB)       // 489
#define SCAN_N (NKEYS * NSCAT)                     // 524288
#define SCAN_BLOCKS (SCAN_N / 1024)                // 512
#define NW 8                 // src windows: src>>16
#define CAP 5120             // winsort LDS capacity (mean 4096, sd 64 -> safe)

// ---------------- xpad: x[N][9] -> xa[N][8] (32B rows) + xb[N] --------------
__global__ void gin_xpad(const float* __restrict__ x,
                         float* __restrict__ xa, float* __restrict__ xb) {
    int i = blockIdx.x * blockDim.x + threadIdx.x;
    const int TOT = N_NODES * IN_DIM;
    if (i < TOT) {
        int n = i / IN_DIM, k = i - n * IN_DIM;
        float val = x[i];
        if (k < 8) xa[n * 8 + k] = val;
        else       xb[n] = val;
    }
}

// ---------------- precompute: v = w2@w3, c = b2.w3, out[g] = b3 -------------
__global__ void gin_precompute(const float* __restrict__ w2,
                               const float* __restrict__ b2,
                               const float* __restrict__ w3,
                               const float* __restrict__ b3,
                               float* __restrict__ out,
                               float* __restrict__ v,
                               float* __restrict__ c) {
    int g = blockIdx.x * blockDim.x + threadIdx.x;
    if (g < N_GRAPHS) out[g] = b3[0];
    if (blockIdx.x == 0) {
        int k = threadIdx.x;
        if (k < HID) {
            float acc = 0.f;
            #pragma unroll
            for (int j = 0; j < HID; ++j) acc += w2[k * HID + j] * w3[j];
            v[k] = acc;
        } else if (k == HID) {
            float acc = 0.f;
            #pragma unroll
            for (int j = 0; j < HID; ++j) acc += b2[j] * w3[j];
            *c = acc;
        }
    }
}

// ---------------- hist: cnt[key*NSCAT + s], key = dst>>8 --------------------
__global__ __launch_bounds__(HSB) void gin_hist(const int* __restrict__ ei,
                                                int* __restrict__ cnt) {
    __shared__ int h[NKEYS];
    const int t = threadIdx.x, s = blockIdx.x;
    for (int b = t; b < NKEYS; b += HSB) h[b] = 0;
    __syncthreads();
    const int* dst = ei + N_EDGES;
    const int e0 = s * CHUNK, e1 = e0 + CHUNK;
    for (int e = e0 + t; e < e1; e += HSB)
        atomicAdd(&h[dst[e] >> 8], 1);
    __syncthreads();
    for (int b = t; b < NKEYS; b += HSB)
        cnt[b * NSCAT + s] = h[b];
}

// ---------------- parallel exclusive scan of cnt[SCAN_N] --------------------
__global__ __launch_bounds__(256) void gin_scan_a(int* __restrict__ cnt,
                                                  int* __restrict__ aux) {
    __shared__ int wtot[4];
    const int t = threadIdx.x, blk = blockIdx.x;
    int4* p = (int4*)(cnt + blk * 1024);
    int4 vv = p[t];
    int s0 = vv.x, s1 = s0 + vv.y, s2 = s1 + vv.z, s3 = s2 + vv.w;
    int lane = t & 63, w = t >> 6;
    int ws = s3;
    #pragma unroll
    for (int off = 1; off < 64; off <<= 1) {
        int o = __shfl_up(ws, off);
        if (lane >= off) ws += o;
    }
    if (lane == 63) wtot[w] = ws;
    __syncthreads();
    int wbase = 0;
    for (int i = 0; i < w; ++i) wbase += wtot[i];
    int excl = wbase + (ws - s3);
    int4 o4;
    o4.x = excl; o4.y = excl + s0; o4.z = excl + s1; o4.w = excl + s2;
    p[t] = o4;
    if (t == 255) aux[blk] = wbase + ws;
}

__global__ __launch_bounds__(64) void gin_scan_b(int* __restrict__ aux) {
    const int t = threadIdx.x;
    int4* p = (int4*)aux;
    int4 a = p[2 * t], bq = p[2 * t + 1];
    int s0 = a.x, s1 = s0 + a.y, s2 = s1 + a.z, s3 = s2 + a.w;
    int s4 = s3 + bq.x, s5 = s4 + bq.y, s6 = s5 + bq.z, s7 = s6 + bq.w;
    int ws = s7;
    #pragma unroll
    for (int off = 1; off < 64; off <<= 1) {
        int o = __shfl_up(ws, off);
        if (t >= off) ws += o;
    }
    int excl = ws - s7;
    int4 o0, o1;
    o0.x = excl; o0.y = excl + s0; o0.z = excl + s1; o0.w = excl + s2;
    o1.x = excl + s3; o1.y = excl + s4; o1.z = excl + s5; o1.w = excl + s6;
    p[2 * t] = o0; p[2 * t + 1] = o1;
}

__global__ __launch_bounds__(256) void gin_scan_c(int* __restrict__ cnt,
                                                  const int* __restrict__ aux) {
    const int t = threadIdx.x, blk = blockIdx.x;
    int base = aux[blk];
    int4* p = (int4*)(cnt + blk * 1024);
    int4 vv = p[t];
    vv.x += base; vv.y += base; vv.z += base; vv.w += base;
    p[t] = vv;
}

// ---------------- scatter: fully LDS-staged, burst flush --------------------
// Stage the whole 31250-edge chunk in LDS at locally-sorted positions, then
// flush each (key,block) region with contiguous stores. Each packed line is
// written in 1-2 bursts instead of ~16 single-edge touches -> low write amp.
// Final positions identical to the unstaged version.
__global__ __launch_bounds__(HSB) void gin_scatter(const int* __restrict__ ei,
                                                   const int* __restrict__ cnt,
                                                   unsigned int* __restrict__ packed) {
    __shared__ int cur[NKEYS];            // 8 KB
    __shared__ unsigned int E[CHUNK];     // 122.1 KB
    __shared__ int wtot[16];
    const int t = threadIdx.x, s = blockIdx.x;
    const int lane = t & 63, wave = t >> 6;

    // local exclusive scan of this block's per-key counts via flat-scan diffs
    const int k0 = 2 * t, k1 = 2 * t + 1;
    const int f0 = k0 * NSCAT + s;
    const int f1 = k1 * NSCAT + s;
    int c0 = cnt[f0 + 1] - cnt[f0];
    int nxt = (f1 + 1 < SCAN_N) ? cnt[f1 + 1] : N_EDGES;
    int c1 = nxt - cnt[f1];
    int sum2 = c0 + c1;
    int ws = sum2;
    #pragma unroll
    for (int off = 1; off < 64; off <<= 1) {
        int o = __shfl_up(ws, off);
        if (lane >= off) ws += o;
    }
    if (lane == 63) wtot[wave] = ws;
    __syncthreads();
    int wbase = 0;
    for (int i = 0; i < wave; ++i) wbase += wtot[i];
    int excl = wbase + ws - sum2;
    cur[k0] = excl;
    cur[k1] = excl + c0;
    __syncthreads();

    // phase 1: place edges into LDS at locally-sorted positions
    const int* src = ei;
    const int* dst = ei + N_EDGES;
    const int e0 = s * CHUNK, e1 = e0 + CHUNK;
    for (int e = e0 + t; e < e1; e += HSB) {
        int d = dst[e];
        int key = d >> 8;
        int lofs = atomicAdd(&cur[key], 1);
        E[lofs] = (unsigned int)src[e] | ((unsigned int)(d & (TILE - 1)) << 19);
    }
    __syncthreads();
    // post-phase1: cur[k] = local end of key k's run; start = cur[k-1] (or 0)

    // phase 2: per-key burst flush with contiguous global stores
    const int KPW = NKEYS / 16;           // 128 keys per wave
    for (int k = wave * KPW; k < (wave + 1) * KPW; ++k) {
        int endl = cur[k];
        int startl = (k > 0) ? cur[k - 1] : 0;
        int m = endl - startl;
        if (m <= 0) continue;
        int gbase = cnt[k * NSCAT + s];
        for (int j = lane; j < m; j += 64)
            packed[gbase + j] = E[startl + j];
    }
}

// ---------------- winsort: reorder each bucket's edges by src window --------
__global__ __launch_bounds__(256) void gin_winsort(unsigned int* __restrict__ packed,
                                                   const int* __restrict__ cnt) {
    __shared__ unsigned int E[CAP];
    __shared__ unsigned int F[CAP];
    __shared__ int cw[NW * 256];
    __shared__ int winBase[NW];
    __shared__ int wt[NW];
    const int t = threadIdx.x, bucket = blockIdx.x;
    const int beg = cnt[bucket * NSCAT];
    const int end = cnt[(bucket + 1) * NSCAT];
    const int n = end - beg;
    if (n > CAP) return;                      // identity fallback (rare/never)

    for (int i = t; i < n; i += 256) E[i] = packed[beg + i];
    __syncthreads();

    int c[NW];
    #pragma unroll
    for (int w = 0; w < NW; ++w) c[w] = 0;
    for (int i = t; i < n; i += 256) { int w = (E[i] & 0x7FFFFu) >> 16; c[w]++; }
    #pragma unroll
    for (int w = 0; w < NW; ++w) cw[w * 256 + t] = c[w];
    __syncthreads();

    const int lane = t & 63, wv = t >> 6;
    for (int rep = 0; rep < 2; ++rep) {
        int w = wv + rep * 4;
        int carry = 0;
        #pragma unroll
        for (int chunkk = 0; chunkk < 4; ++chunkk) {
            int idx = chunkk * 64 + lane;
            int val = cw[w * 256 + idx];
            int sc = val;
            #pragma unroll
            for (int off = 1; off < 64; off <<= 1) {
                int o = __shfl_up(sc, off);
                if (lane >= off) sc += o;
            }
            cw[w * 256 + idx] = sc - val + carry;
            carry += __shfl(sc, 63);
        }
        if (lane == 0) wt[w] = carry;
    }
    __syncthreads();
    if (t == 0) {
        int run = 0;
        #pragma unroll
        for (int w = 0; w < NW; ++w) { winBase[w] = run; run += wt[w]; }
    }
    __syncthreads();

    int runc[NW];
    #pragma unroll
    for (int w = 0; w < NW; ++w) runc[w] = 0;
    for (int i = t; i < n; i += 256) {
        unsigned int pk = E[i];
        int w = (pk & 0x7FFFFu) >> 16;
        int pos = winBase[w] + cw[w * 256 + t] + runc[w]++;
        F[pos] = pk;
    }
    __syncthreads();
    for (int i = t; i < n; i += 256) packed[beg + i] = F[i];
}

// ---------------- reduce: wave-private tile, NO aggregation atomics ---------
__global__ __launch_bounds__(RB) void gin_reduce(
    const unsigned int* __restrict__ packed,
    const int* __restrict__ cnt,
    const float* __restrict__ xa,
    const float* __restrict__ xb,
    const int* __restrict__ batch,
    const float* __restrict__ w1,
    const float* __restrict__ b1,
    const float* __restrict__ v,
    const float* __restrict__ c,
    float* __restrict__ out)
{
    __shared__ float tile[WPB * TILE * TSR];   // 48 KB, one 12 KB slice per wave
    __shared__ float w1s[IN_DIM * HID];
    __shared__ float b1s[HID];
    __shared__ float vs[HID];
    __shared__ float cs;

    const int t = threadIdx.x;
    const int wave = t >> 6, lane = t & 63;

    for (int i = t; i < WPB * TILE * TSR; i += RB) tile[i] = 0.f;
    for (int i = t; i < IN_DIM * HID; i += RB) w1s[i] = w1[i];
    if (t < HID) { b1s[t] = b1[t]; vs[t] = v[t]; }
    if (t == 0) cs = *c;
    __syncthreads();

    const int bucket = blockIdx.x * WPB + wave;
    float* tw = tile + wave * TILE * TSR;
    const int beg = cnt[bucket * NSCAT];
    const int end = cnt[(bucket + 1) * NSCAT];   // padded keys hold N_EDGES

    for (int p0 = beg; p0 < end; p0 += 64) {
        int p = p0 + lane;
        bool valid = p < end;
        unsigned int pk = valid ? packed[p] : 0u;
        int local = (int)(pk >> 19);             // 0..255
        int src = (int)(pk & 0x7FFFFu);
        const float4* xr = (const float4*)(xa + (size_t)src * 8);
        float4 a0 = xr[0], a1 = xr[1];
        float a2 = xb[src];

        unsigned long long active = __ballot(valid);
        while (active) {
            unsigned long long m = active;
            #pragma unroll
            for (int bq = 0; bq < 8; ++bq) {
                unsigned long long bal = __ballot((local >> bq) & 1);
                m &= ((local >> bq) & 1) ? bal : ~bal;
            }
            unsigned long long mybit = 1ULL << lane;
            bool lead = ((active & mybit) != 0ULL) && ((m & (mybit - 1ULL)) == 0ULL);
            unsigned long long lmask = __ballot(lead);
            if (lead) {
                float4* row = (float4*)(tw + local * TSR);
                float4 r0 = row[0], r1 = row[1];
                float r2 = tw[local * TSR + 8];
                r0.x += a0.x; r0.y += a0.y; r0.z += a0.z; r0.w += a0.w;
                r1.x += a1.x; r1.y += a1.y; r1.z += a1.z; r1.w += a1.w;
                row[0] = r0; row[1] = r1;
                tw[local * TSR + 8] = r2 + a2;
            }
            active &= ~lmask;
        }
    }
    // no barrier needed: tile slice is wave-private from here on

    // fused MLP + scalar collapse + segmented pooled reduction
    #pragma unroll
    for (int g = 0; g < TILE / 64; ++g) {
        int n = g * 64 + lane;
        int node = bucket * TILE + n;
        float s = 0.f;
        int b = -1;
        if (node < N_NODES) {
            const float4* xr = (const float4*)(xa + (size_t)node * 8);
            float4 q0 = xr[0], q1 = xr[1];
            float tv[IN_DIM];
            tv[0] = q0.x + tw[n * TSR + 0];
            tv[1] = q0.y + tw[n * TSR + 1];
            tv[2] = q0.z + tw[n * TSR + 2];
            tv[3] = q0.w + tw[n * TSR + 3];
            tv[4] = q1.x + tw[n * TSR + 4];
            tv[5] = q1.y + tw[n * TSR + 5];
            tv[6] = q1.z + tw[n * TSR + 6];
            tv[7] = q1.w + tw[n * TSR + 7];
            tv[8] = xb[node] + tw[n * TSR + 8];
            s = cs;
            #pragma unroll
            for (int j = 0; j < HID; ++j) {
                float z = b1s[j];
                #pragma unroll
                for (int k = 0; k < IN_DIM; ++k)
                    z = fmaf(tv[k], w1s[k * HID + j], z);
                s += fmaxf(z, 0.f) * vs[j];
            }
            b = batch[node];
        }
        #pragma unroll
        for (int off = 1; off < 64; off <<= 1) {
            float so = __shfl_up(s, off);
            int bo = __shfl_up(b, off);
            if (lane >= off && bo == b) s += so;
        }
        int nb = __shfl_down(b, 1);
        bool tail = (lane == 63) || (nb != b);
        if (tail && b >= 0) atomicAdd(&out[b], s);
    }
}

extern "C" void kernel_launch(void* const* d_in, const int* in_sizes, int n_in,
                              void* d_out, int out_size, void* d_ws, size_t ws_size,
                              hipStream_t stream) {
    const float* x     = (const float*)d_in[0];
    const int*   ei    = (const int*)d_in[1];
    const int*   batch = (const int*)d_in[2];
    const float* w1    = (const float*)d_in[3];
    const float* b1    = (const float*)d_in[4];
    const float* w2    = (const float*)d_in[5];
    const float* b2    = (const float*)d_in[6];
    const float* w3    = (const float*)d_in[7];
    const float* b3    = (const float*)d_in[8];
    float* out = (float*)d_out;

    // workspace (~52.1 MB)
    float* xa = (float*)d_ws;                                           // 16 MB
    float* xb = xa + (size_t)N_NODES * 8;                               // 2 MB
    unsigned int* packed = (unsigned int*)(xb + N_NODES);               // 32 MB
    int* cnt = (int*)(packed + N_EDGES);                                // 2 MB
    int* aux = cnt + SCAN_N;                                            // 512 ints
    float* v = (float*)(aux + SCAN_BLOCKS);                             // 64 floats
    float* c = v + HID;                                                 // 1 float

    gin_xpad<<<(N_NODES * IN_DIM + 255) / 256, 256, 0, stream>>>(x, xa, xb);
    gin_precompute<<<(N_GRAPHS + 255) / 256, 256, 0, stream>>>(w2, b2, w3, b3, out, v, c);
    gin_hist<<<NSCAT, HSB, 0, stream>>>(ei, cnt);
    gin_scan_a<<<SCAN_BLOCKS, 256, 0, stream>>>(cnt, aux);
    gin_scan_b<<<1, 64, 0, stream>>>(aux);
    gin_scan_c<<<SCAN_BLOCKS, 256, 0, stream>>>(cnt, aux);
    gin_scatter<<<NSCAT, HSB, 0, stream>>>(ei, cnt, packed);
    gin_winsort<<<NKEYS_USED, 256, 0, stream>>>(packed, cnt);
    gin_reduce<<<RGRID, RB, 0, stream>>>(packed, cnt, xa, xb, batch, w1, b1, v, c, out);
}